// Round 7
// baseline (390.347 us; speedup 1.0000x reference)
//
#include <hip/hip_runtime.h>
#include <hip/hip_bf16.h>

#define N_SEQ 4096
#define DIMM  1536
#define NH    4
#define DK    64
#define HD    256     // NH*DK
#define QK_SCALE 0.125f

typedef __bf16 bf16x8 __attribute__((ext_vector_type(8)));
typedef unsigned short u16;
typedef u16   u16x8  __attribute__((ext_vector_type(8)));
typedef float f32x4  __attribute__((ext_vector_type(4)));

__device__ inline float b2f(u16 u){
    union { float f; unsigned int i; } v; v.i = ((unsigned int)u) << 16; return v.f;
}
__device__ inline u16 f2b(float f){
    unsigned int x = __builtin_bit_cast(unsigned int, f);
    unsigned int r = (x + 0x7fffu + ((x >> 16) & 1u)) >> 16;
    return (u16)r;
}
__device__ inline bf16x8 ldfrag(const u16* p){
    return __builtin_bit_cast(bf16x8, *(const u16x8*)p);
}

// ---------------------------------------------------------------------------
// rel_k[c, h*64+d] = (positions @ W_rel_k)[c, :] in bf16; row 8191 = 0.
// positions[c, f<32] = (cw[f] > |dist|), positions[c, 32+f] = sign * same.
// ---------------------------------------------------------------------------
__global__ __launch_bounds__(256) void relk_kernel(const float* __restrict__ Wrel,
                                                   u16* __restrict__ relk){
    int c = blockIdx.x;
    int t = threadIdx.x;
    if (c == 2 * N_SEQ - 1){ relk[(size_t)c * HD + t] = 0; return; }
    int d = c - (N_SEQ - 1);
    float ad = fabsf((float)d);
    float sgn = (d > 0) ? 1.f : ((d < 0) ? -1.f : 0.f);
    float lg = logf((float)(N_SEQ + 1)) * (1.0f / 32.0f);
    float acc = 0.f;
    for (int j = 0; j < 32; ++j){
        float cw = expf(lg * (float)(j + 1)) - 1.0f;
        if (cw > ad){
            acc += Wrel[j * HD + t] + sgn * Wrel[(32 + j) * HD + t];
        }
    }
    relk[(size_t)c * HD + t] = f2b(acc);
}

// ---------------------------------------------------------------------------
// Fused QKV projection: C = X @ [Wq|Wk|Wv], M=4096, K=1536, N=768.
// fp32 inputs converted to bf16 at staging; Q scaled by QK_SCALE. bf16 out.
// ---------------------------------------------------------------------------
__global__ __launch_bounds__(256) void qkv_kernel(const float* __restrict__ X,
    const float* __restrict__ Wq, const float* __restrict__ Wk, const float* __restrict__ Wv,
    u16* __restrict__ Q, u16* __restrict__ K, u16* __restrict__ V){
    __shared__ __align__(16) u16 xs[64 * 72];
    __shared__ __align__(16) u16 bs[64 * 72];
    int m0   = blockIdx.y * 64;
    int wsel = blockIdx.x >> 2;
    int n0   = (blockIdx.x & 3) * 64;
    const float* W = (wsel == 0) ? Wq : (wsel == 1 ? Wk : Wv);
    u16*       dst = (wsel == 0) ? Q  : (wsel == 1 ? K  : V);
    int t = threadIdx.x;
    int w = t >> 6, lane = t & 63, qd = lane >> 4, l15 = lane & 15;
    f32x4 acc[4] = {{0,0,0,0},{0,0,0,0},{0,0,0,0},{0,0,0,0}};
    for (int k0 = 0; k0 < DIMM; k0 += 64){
        #pragma unroll
        for (int rep = 0; rep < 2; ++rep){
            int vid = rep * 256 + t;
            int r  = vid >> 3;
            int cv = (vid & 7) * 8;
            size_t xi = (size_t)(m0 + r) * DIMM + k0 + cv;
            size_t wi = (size_t)(k0 + r) * HD + n0 + cv;
            f32x4 xa = *(const f32x4*)(X + xi), xb = *(const f32x4*)(X + xi + 4);
            f32x4 wa = *(const f32x4*)(W + wi), wb = *(const f32x4*)(W + wi + 4);
            u16x8 xv, wv;
            #pragma unroll
            for (int e = 0; e < 4; ++e){
                xv[e] = f2b(xa[e]); xv[4 + e] = f2b(xb[e]);
                wv[e] = f2b(wa[e]); wv[4 + e] = f2b(wb[e]);
            }
            *(u16x8*)&xs[r * 72 + cv] = xv;
            #pragma unroll
            for (int e = 0; e < 8; ++e) bs[(cv + e) * 72 + r] = wv[e];
        }
        __syncthreads();
        bf16x8 a0 = ldfrag(&xs[(w * 16 + l15) * 72 +  0 + qd * 8]);
        bf16x8 a1 = ldfrag(&xs[(w * 16 + l15) * 72 + 32 + qd * 8]);
        #pragma unroll
        for (int nt = 0; nt < 4; ++nt){
            bf16x8 b0 = ldfrag(&bs[(nt * 16 + l15) * 72 +  0 + qd * 8]);
            bf16x8 b1 = ldfrag(&bs[(nt * 16 + l15) * 72 + 32 + qd * 8]);
            acc[nt] = __builtin_amdgcn_mfma_f32_16x16x32_bf16(a0, b0, acc[nt], 0, 0, 0);
            acc[nt] = __builtin_amdgcn_mfma_f32_16x16x32_bf16(a1, b1, acc[nt], 0, 0, 0);
        }
        __syncthreads();
    }
    float sc = (wsel == 0) ? QK_SCALE : 1.0f;
    #pragma unroll
    for (int nt = 0; nt < 4; ++nt)
        #pragma unroll
        for (int reg = 0; reg < 4; ++reg){
            int row = m0 + w * 16 + qd * 4 + reg;
            int col = n0 + nt * 16 + l15;
            dst[(size_t)row * HD + col] = f2b(acc[nt][reg] * sc);
        }
}

// ---------------------------------------------------------------------------
// Flash attention with relative-position logits (MFMA).
// Block = (64 q-rows, one head), 4 waves. K-tiles of 64.
// ---------------------------------------------------------------------------
__global__ __launch_bounds__(256) void attn_kernel(const u16* __restrict__ Q,
    const u16* __restrict__ Kg, const u16* __restrict__ Vg, const u16* __restrict__ RK,
    const float* __restrict__ CB, const float* __restrict__ PB, u16* __restrict__ O){
    __shared__ __align__(16) unsigned char smem[64512];
    u16* qcs = (u16*)(smem + 0);        // 64*72*2 = 9216   (init only)
    u16* qps = (u16*)(smem + 9216);     // 9216             (init only)
    u16* Ts  = (u16*)(smem + 0);        // 64*136*2 = 17408 (overlays qcs/qps)
    u16* Ks  = (u16*)(smem + 18432);    // 9216
    u16* Vts = (u16*)(smem + 27648);    // 9216
    u16* Ps  = (u16*)(smem + 36864);    // 9216
    u16* Rs  = (u16*)(smem + 46080);    // 128*72*2 = 18432 -> end 64512

    int i0 = blockIdx.x * 64;
    int h  = blockIdx.y;
    int t  = threadIdx.x;
    int w = t >> 6, lane = t & 63, qd = lane >> 4, l15 = lane & 15;

    // stage qc = q + content_bias, qp = q + pos_bias (q already scaled)
    #pragma unroll
    for (int rep = 0; rep < 2; ++rep){
        int vid = rep * 256 + t;
        int r  = vid >> 3;
        int cv = (vid & 7) * 8;
        u16x8 qv = *(const u16x8*)&Q[(size_t)(i0 + r) * HD + h * DK + cv];
        u16x8 oc, op;
        #pragma unroll
        for (int e = 0; e < 8; ++e){
            float qf = b2f(qv[e]);
            oc[e] = f2b(qf + CB[h * DK + cv + e]);
            op[e] = f2b(qf + PB[h * DK + cv + e]);
        }
        *(u16x8*)&qcs[r * 72 + cv] = oc;
        *(u16x8*)&qps[r * 72 + cv] = op;
    }
    __syncthreads();
    bf16x8 aqc[2], aqp[2];
    #pragma unroll
    for (int kc = 0; kc < 2; ++kc){
        aqc[kc] = ldfrag(&qcs[(w * 16 + l15) * 72 + kc * 32 + qd * 8]);
        aqp[kc] = ldfrag(&qps[(w * 16 + l15) * 72 + kc * 32 + qd * 8]);
    }

    float mrow[4] = {-1e9f, -1e9f, -1e9f, -1e9f};
    float lrow[4] = {0.f, 0.f, 0.f, 0.f};
    f32x4 oacc[4] = {{0,0,0,0},{0,0,0,0},{0,0,0,0},{0,0,0,0}};
    int iiBase = w * 16 + qd * 4;

    for (int j0 = 0; j0 < N_SEQ; j0 += 64){
        int c0 = (N_SEQ - 1) + j0 - i0 - 63;   // in [0, 8064]; c0+127 <= 8191
        // stage K (row-major) and V (transposed)
        #pragma unroll
        for (int rep = 0; rep < 2; ++rep){
            int vid = rep * 256 + t;
            int r  = vid >> 3;
            int cv = (vid & 7) * 8;
            *(u16x8*)&Ks[r * 72 + cv] = *(const u16x8*)&Kg[(size_t)(j0 + r) * HD + h * DK + cv];
            u16x8 vv = *(const u16x8*)&Vg[(size_t)(j0 + r) * HD + h * DK + cv];
            #pragma unroll
            for (int e = 0; e < 8; ++e) Vts[(cv + e) * 72 + r] = vv[e];
        }
        // stage rel_k window: 128 rows
        #pragma unroll
        for (int rep = 0; rep < 4; ++rep){
            int vid = rep * 256 + t;
            int r  = vid >> 3;          // 0..127
            int cv = (vid & 7) * 8;
            *(u16x8*)&Rs[r * 72 + cv] = *(const u16x8*)&RK[(size_t)(c0 + r) * HD + h * DK + cv];
        }
        __syncthreads();

        // content logits S (16x64 strip per wave)
        f32x4 s[4] = {{0,0,0,0},{0,0,0,0},{0,0,0,0},{0,0,0,0}};
        #pragma unroll
        for (int nt = 0; nt < 4; ++nt)
            #pragma unroll
            for (int kc = 0; kc < 2; ++kc){
                bf16x8 b = ldfrag(&Ks[(nt * 16 + l15) * 72 + kc * 32 + qd * 8]);
                s[nt] = __builtin_amdgcn_mfma_f32_16x16x32_bf16(aqc[kc], b, s[nt], 0, 0, 0);
            }
        // rel strip T (16x128 per wave) -> LDS (bf16)
        #pragma unroll
        for (int tt = 0; tt < 8; ++tt){
            f32x4 tv = {0, 0, 0, 0};
            #pragma unroll
            for (int kc = 0; kc < 2; ++kc){
                bf16x8 b = ldfrag(&Rs[(tt * 16 + l15) * 72 + kc * 32 + qd * 8]);
                tv = __builtin_amdgcn_mfma_f32_16x16x32_bf16(aqp[kc], b, tv, 0, 0, 0);
            }
            #pragma unroll
            for (int reg = 0; reg < 4; ++reg)
                Ts[(iiBase + reg) * 136 + tt * 16 + l15] = f2b(tv[reg]);
        }
        __syncthreads();

        // merge content + gathered rel logits: rel col = jj - ii + 63 in [0,126]
        float sv[4][4];
        #pragma unroll
        for (int nt = 0; nt < 4; ++nt)
            #pragma unroll
            for (int reg = 0; reg < 4; ++reg){
                int ii = iiBase + reg;
                int jj = nt * 16 + l15;
                sv[nt][reg] = s[nt][reg] + b2f(Ts[ii * 136 + (jj - ii + 63)]);
            }

        // online softmax
        float mnew[4], alpha[4];
        #pragma unroll
        for (int reg = 0; reg < 4; ++reg){
            float mx = fmaxf(fmaxf(sv[0][reg], sv[1][reg]), fmaxf(sv[2][reg], sv[3][reg]));
            #pragma unroll
            for (int d = 1; d < 16; d <<= 1) mx = fmaxf(mx, __shfl_xor(mx, d));
            mnew[reg]  = fmaxf(mrow[reg], mx);
            alpha[reg] = __expf(mrow[reg] - mnew[reg]);
            mrow[reg]  = mnew[reg];
        }
        float psum[4] = {0.f, 0.f, 0.f, 0.f};
        #pragma unroll
        for (int nt = 0; nt < 4; ++nt)
            #pragma unroll
            for (int reg = 0; reg < 4; ++reg){
                float p = __expf(sv[nt][reg] - mnew[reg]);
                psum[reg] += p;
                Ps[(iiBase + reg) * 72 + nt * 16 + l15] = f2b(p);
            }
        #pragma unroll
        for (int reg = 0; reg < 4; ++reg){
            float ssum = psum[reg];
            #pragma unroll
            for (int d = 1; d < 16; d <<= 1) ssum += __shfl_xor(ssum, d);
            lrow[reg] = lrow[reg] * alpha[reg] + ssum;
        }
        #pragma unroll
        for (int nt = 0; nt < 4; ++nt)
            #pragma unroll
            for (int reg = 0; reg < 4; ++reg)
                oacc[nt][reg] *= alpha[reg];
        __syncthreads();

        // O += P @ V
        #pragma unroll
        for (int kc = 0; kc < 2; ++kc){
            bf16x8 a = ldfrag(&Ps[(w * 16 + l15) * 72 + kc * 32 + qd * 8]);
            #pragma unroll
            for (int nt = 0; nt < 4; ++nt){
                bf16x8 b = ldfrag(&Vts[(nt * 16 + l15) * 72 + kc * 32 + qd * 8]);
                oacc[nt] = __builtin_amdgcn_mfma_f32_16x16x32_bf16(a, b, oacc[nt], 0, 0, 0);
            }
        }
        __syncthreads();
    }

    #pragma unroll
    for (int nt = 0; nt < 4; ++nt)
        #pragma unroll
        for (int reg = 0; reg < 4; ++reg){
            int ii = iiBase + reg;
            float denom = fmaxf(lrow[reg], 1e-30f);
            O[(size_t)(i0 + ii) * HD + h * DK + nt * 16 + l15] = f2b(oacc[nt][reg] / denom);
        }
}

// ---------------------------------------------------------------------------
// Output projection: out = Oattn @ Wo + bo. fp32 weights/bias/output.
// Rows [m_base + blockIdx.y*64, +64). K=256, N=1536.
// ---------------------------------------------------------------------------
__global__ __launch_bounds__(256) void oproj_kernel(const u16* __restrict__ A,
    const float* __restrict__ Wo, const float* __restrict__ bo,
    float* __restrict__ out, int m_base){
    __shared__ __align__(16) u16 xs[64 * 72];
    __shared__ __align__(16) u16 bs[64 * 72];
    int m0 = m_base + blockIdx.y * 64;
    int n0 = blockIdx.x * 64;
    int t = threadIdx.x;
    int w = t >> 6, lane = t & 63, qd = lane >> 4, l15 = lane & 15;
    f32x4 acc[4] = {{0,0,0,0},{0,0,0,0},{0,0,0,0},{0,0,0,0}};
    for (int k0 = 0; k0 < HD; k0 += 64){
        #pragma unroll
        for (int rep = 0; rep < 2; ++rep){
            int vid = rep * 256 + t;
            int r  = vid >> 3;
            int cv = (vid & 7) * 8;
            *(u16x8*)&xs[r * 72 + cv] = *(const u16x8*)&A[(size_t)(m0 + r) * HD + k0 + cv];
            size_t wi = (size_t)(k0 + r) * DIMM + n0 + cv;
            f32x4 wa = *(const f32x4*)(Wo + wi), wb = *(const f32x4*)(Wo + wi + 4);
            u16x8 wv;
            #pragma unroll
            for (int e = 0; e < 4; ++e){ wv[e] = f2b(wa[e]); wv[4 + e] = f2b(wb[e]); }
            #pragma unroll
            for (int e = 0; e < 8; ++e) bs[(cv + e) * 72 + r] = wv[e];
        }
        __syncthreads();
        bf16x8 a0 = ldfrag(&xs[(w * 16 + l15) * 72 +  0 + qd * 8]);
        bf16x8 a1 = ldfrag(&xs[(w * 16 + l15) * 72 + 32 + qd * 8]);
        #pragma unroll
        for (int nt = 0; nt < 4; ++nt){
            bf16x8 b0 = ldfrag(&bs[(nt * 16 + l15) * 72 +  0 + qd * 8]);
            bf16x8 b1 = ldfrag(&bs[(nt * 16 + l15) * 72 + 32 + qd * 8]);
            acc[nt] = __builtin_amdgcn_mfma_f32_16x16x32_bf16(a0, b0, acc[nt], 0, 0, 0);
            acc[nt] = __builtin_amdgcn_mfma_f32_16x16x32_bf16(a1, b1, acc[nt], 0, 0, 0);
        }
        __syncthreads();
    }
    #pragma unroll
    for (int nt = 0; nt < 4; ++nt)
        #pragma unroll
        for (int reg = 0; reg < 4; ++reg){
            int row = m0 + w * 16 + qd * 4 + reg;
            int col = n0 + nt * 16 + l15;
            out[(size_t)row * DIMM + col] = acc[nt][reg] + bo[col];
        }
}

extern "C" void kernel_launch(void* const* d_in, const int* in_sizes, int n_in,
                              void* d_out, int out_size, void* d_ws, size_t ws_size,
                              hipStream_t stream){
    const float* X  = (const float*)d_in[0];
    const float* Wq = (const float*)d_in[1];
    const float* Wk = (const float*)d_in[2];
    const float* Wv = (const float*)d_in[3];
    const float* Wr = (const float*)d_in[4];
    const float* Wo = (const float*)d_in[5];
    const float* bo = (const float*)d_in[6];
    const float* CB = (const float*)d_in[7];
    const float* PB = (const float*)d_in[8];
    float* out = (float*)d_out;

    // d_out = 6,291,456 fp32 = 24 MB = 12,582,912 u16 slots. bf16 scratch
    // lives in the TAIL (u16 indices), all dead or consumed in row order
    // before the fp32 out-writes reach it:
    //   Q    u16 [ 6291456,  7340032)
    //   K    u16 [ 7340032,  8388608)
    //   V    u16 [ 8388608,  9437184)
    //   RK   u16 [ 9437184, 11534336)   (8192 x 256)
    //   Oatt u16 [11534336, 12582912)
    // fp32 out row m occupies u16 [3072m, 3072(m+1)); Oatt row m starts at
    // u16 11534336 + 256m.
    u16* base = (u16*)d_out;
    u16* Q    = base + 6291456;
    u16* K    = base + 7340032;
    u16* V    = base + 8388608;
    u16* RK   = base + 9437184;
    u16* Oatt = base + 11534336;

    relk_kernel<<<dim3(2 * N_SEQ), 256, 0, stream>>>(Wr, RK);
    qkv_kernel<<<dim3(12, 64), 256, 0, stream>>>(X, Wq, Wk, Wv, Q, K, V);
    attn_kernel<<<dim3(64, NH), 256, 0, stream>>>(Q, K, V, RK, CB, PB, Oatt);

    // Copy the last 64 Oatt rows (32 KB) to d_ws for the final launch
    // (within-launch blocks would otherwise race writes vs. reads there).
    u16* Acpy = (u16*)d_ws;
    hipMemcpyAsync(Acpy, Oatt + (size_t)4032 * HD, (size_t)64 * HD * sizeof(u16),
                   hipMemcpyDeviceToDevice, stream);

    // oproj split (non-clobber arithmetic, u16 units):
    //  L1 rows [0,3712):    writes end 3072*3712 = 11,403,264 <= 11,534,336
    //     (Oatt start) — never touches Oatt.                              safe
    //  L2 rows [3712,4032): writes end 3072*4032 = 12,386,304 <= 12,484,608
    //     (Oatt row 3712 start) — clobbers only Oatt rows < 3712 (dead) and
    //     leaves rows >= 4032 (12,566,528+) intact for L3.                safe
    //  L3 rows [4032,4096): reads the ws copy; writes anywhere.           safe
    oproj_kernel<<<dim3(24, 58), 256, 0, stream>>>(Oatt, Wo, bo, out, 0);
    oproj_kernel<<<dim3(24,  5), 256, 0, stream>>>(Oatt, Wo, bo, out, 3712);
    oproj_kernel<<<dim3(24,  1), 256, 0, stream>>>(Acpy - (size_t)4032 * HD,
                                                   Wo, bo, out, 4032);
}

// Round 8
// 298.850 us; speedup vs baseline: 1.3062x; 1.3062x over previous
//
#include <hip/hip_runtime.h>
#include <hip/hip_bf16.h>

#define N_SEQ 4096
#define DIMM  1536
#define NH    4
#define DK    64
#define HD    256     // NH*DK
#define QK_SCALE 0.125f

typedef __bf16 bf16x8 __attribute__((ext_vector_type(8)));
typedef unsigned short u16;
typedef u16   u16x8  __attribute__((ext_vector_type(8)));
typedef u16   u16x4  __attribute__((ext_vector_type(4)));
typedef float f32x4  __attribute__((ext_vector_type(4)));

__device__ inline float b2f(u16 u){
    union { float f; unsigned int i; } v; v.i = ((unsigned int)u) << 16; return v.f;
}
__device__ inline u16 f2b(float f){
    unsigned int x = __builtin_bit_cast(unsigned int, f);
    unsigned int r = (x + 0x7fffu + ((x >> 16) & 1u)) >> 16;
    return (u16)r;
}
__device__ inline bf16x8 ldfrag(const u16* p){
    return __builtin_bit_cast(bf16x8, *(const u16x8*)p);
}

// ---------------------------------------------------------------------------
// rel_k[c, h*64+d] = (positions @ W_rel_k)[c, :] in bf16; row 8191 = 0.
// ---------------------------------------------------------------------------
__global__ __launch_bounds__(256) void relk_kernel(const float* __restrict__ Wrel,
                                                   u16* __restrict__ relk){
    __shared__ float cw[32];
    int c = blockIdx.x;
    int t = threadIdx.x;
    if (t < 32){
        float lg = logf((float)(N_SEQ + 1)) * (1.0f / 32.0f);
        cw[t] = expf(lg * (float)(t + 1)) - 1.0f;
    }
    __syncthreads();
    float acc = 0.f;
    if (c != 2 * N_SEQ - 1){
        int d = c - (N_SEQ - 1);
        float ad = fabsf((float)d);
        float sgn = (d > 0) ? 1.f : ((d < 0) ? -1.f : 0.f);
        for (int j = 0; j < 32; ++j)
            if (cw[j] > ad)
                acc += Wrel[j * HD + t] + sgn * Wrel[(32 + j) * HD + t];
    }
    relk[(size_t)c * HD + t] = f2b(acc);
}

// ---------------------------------------------------------------------------
// Fused QKV projection: M=4096, K=1536, N=768. fp32 in, bf16 out.
// Q scaled by QK_SCALE. V written TRANSPOSED: Vt[(h*64+d)*4096 + j].
// ---------------------------------------------------------------------------
__global__ __launch_bounds__(256) void qkv_kernel(const float* __restrict__ X,
    const float* __restrict__ Wq, const float* __restrict__ Wk, const float* __restrict__ Wv,
    u16* __restrict__ Q, u16* __restrict__ K, u16* __restrict__ Vt){
    __shared__ __align__(16) u16 xs[64 * 72];
    __shared__ __align__(16) u16 bs[64 * 72];
    int m0   = blockIdx.y * 64;
    int wsel = blockIdx.x >> 2;
    int n0   = (blockIdx.x & 3) * 64;
    const float* W = (wsel == 0) ? Wq : (wsel == 1 ? Wk : Wv);
    int t = threadIdx.x;
    int w = t >> 6, lane = t & 63, qd = lane >> 4, l15 = lane & 15;
    f32x4 acc[4] = {{0,0,0,0},{0,0,0,0},{0,0,0,0},{0,0,0,0}};
    for (int k0 = 0; k0 < DIMM; k0 += 64){
        #pragma unroll
        for (int rep = 0; rep < 2; ++rep){
            int vid = rep * 256 + t;
            int r  = vid >> 3;
            int cv = (vid & 7) * 8;
            size_t xi = (size_t)(m0 + r) * DIMM + k0 + cv;
            size_t wi = (size_t)(k0 + r) * HD + n0 + cv;
            f32x4 xa = *(const f32x4*)(X + xi), xb = *(const f32x4*)(X + xi + 4);
            f32x4 wa = *(const f32x4*)(W + wi), wb = *(const f32x4*)(W + wi + 4);
            u16x8 xv, wv;
            #pragma unroll
            for (int e = 0; e < 4; ++e){
                xv[e] = f2b(xa[e]); xv[4 + e] = f2b(xb[e]);
                wv[e] = f2b(wa[e]); wv[4 + e] = f2b(wb[e]);
            }
            *(u16x8*)&xs[r * 72 + cv] = xv;
            #pragma unroll
            for (int e = 0; e < 8; ++e) bs[(cv + e) * 72 + r] = wv[e];
        }
        __syncthreads();
        bf16x8 a0 = ldfrag(&xs[(w * 16 + l15) * 72 +  0 + qd * 8]);
        bf16x8 a1 = ldfrag(&xs[(w * 16 + l15) * 72 + 32 + qd * 8]);
        #pragma unroll
        for (int nt = 0; nt < 4; ++nt){
            bf16x8 b0 = ldfrag(&bs[(nt * 16 + l15) * 72 +  0 + qd * 8]);
            bf16x8 b1 = ldfrag(&bs[(nt * 16 + l15) * 72 + 32 + qd * 8]);
            acc[nt] = __builtin_amdgcn_mfma_f32_16x16x32_bf16(a0, b0, acc[nt], 0, 0, 0);
            acc[nt] = __builtin_amdgcn_mfma_f32_16x16x32_bf16(a1, b1, acc[nt], 0, 0, 0);
        }
        __syncthreads();
    }
    if (wsel == 2){
        // transposed store: col=(h*64+d) fixed per lane/nt, 4 consecutive j
        int row0 = m0 + w * 16 + qd * 4;
        #pragma unroll
        for (int nt = 0; nt < 4; ++nt){
            int col = n0 + nt * 16 + l15;
            u16x4 pv;
            #pragma unroll
            for (int reg = 0; reg < 4; ++reg) pv[reg] = f2b(acc[nt][reg]);
            *(u16x4*)&Vt[(size_t)col * N_SEQ + row0] = pv;
        }
    } else {
        u16* dst = (wsel == 0) ? Q : K;
        float sc = (wsel == 0) ? QK_SCALE : 1.0f;
        #pragma unroll
        for (int nt = 0; nt < 4; ++nt)
            #pragma unroll
            for (int reg = 0; reg < 4; ++reg){
                int row = m0 + w * 16 + qd * 4 + reg;
                int col = n0 + nt * 16 + l15;
                dst[(size_t)row * HD + col] = f2b(acc[nt][reg] * sc);
            }
    }
}

// ---------------------------------------------------------------------------
// Flash attention, K-split 2-way. Block = (64 q-rows, head, half).
// 2 barriers per K-tile; next-tile global loads prefetched into registers.
// Writes UNNORMALIZED partial O + per-row (m, l) to fp32 scratch.
// ---------------------------------------------------------------------------
__global__ __launch_bounds__(256) void attn_kernel(const u16* __restrict__ Q,
    const u16* __restrict__ Kg, const u16* __restrict__ Vt, const u16* __restrict__ RK,
    const float* __restrict__ CB, const float* __restrict__ PB,
    float* __restrict__ Opart, float* __restrict__ mpart, float* __restrict__ lpart){
    __shared__ __align__(16) unsigned char smem[64512];
    u16* qcs = (u16*)(smem + 0);        // 64*72*2 = 9216   (init only)
    u16* qps = (u16*)(smem + 9216);     // 9216             (init only)
    u16* Ts  = (u16*)(smem + 0);        // 64*136*2 = 17408 (overlays qcs/qps)
    u16* Ks  = (u16*)(smem + 18432);    // 9216
    u16* Vts = (u16*)(smem + 27648);    // 9216
    u16* Ps  = (u16*)(smem + 36864);    // 9216
    u16* Rs  = (u16*)(smem + 46080);    // 128*72*2 = 18432 -> end 64512

    int i0   = blockIdx.x * 64;
    int h    = blockIdx.y;
    int half = blockIdx.z;
    int bid  = blockIdx.x * NH + h;
    int jbase = half * (N_SEQ / 2);
    const int NT = (N_SEQ / 2) / 64;    // 32 tiles
    int t = threadIdx.x;
    int w = t >> 6, lane = t & 63, qd = lane >> 4, l15 = lane & 15;

    // ---- init: qc = q + content_bias, qp = q + pos_bias (q pre-scaled) ----
    #pragma unroll
    for (int rep = 0; rep < 2; ++rep){
        int vid = rep * 256 + t;
        int r  = vid >> 3;
        int cv = (vid & 7) * 8;
        u16x8 qv = *(const u16x8*)&Q[(size_t)(i0 + r) * HD + h * DK + cv];
        u16x8 oc, op;
        #pragma unroll
        for (int e = 0; e < 8; ++e){
            float qf = b2f(qv[e]);
            oc[e] = f2b(qf + CB[h * DK + cv + e]);
            op[e] = f2b(qf + PB[h * DK + cv + e]);
        }
        *(u16x8*)&qcs[r * 72 + cv] = oc;
        *(u16x8*)&qps[r * 72 + cv] = op;
    }
    __syncthreads();
    bf16x8 aqc[2], aqp[2];
    #pragma unroll
    for (int kc = 0; kc < 2; ++kc){
        aqc[kc] = ldfrag(&qcs[(w * 16 + l15) * 72 + kc * 32 + qd * 8]);
        aqp[kc] = ldfrag(&qps[(w * 16 + l15) * 72 + kc * 32 + qd * 8]);
    }

    // ---- staging helpers (register prefetch) ----
    int sr = t >> 3, scv = (t & 7) * 8;
    u16x8 kr0, kr1, vr0, vr1, rr0, rr1, rr2, rr3;
    auto LOAD = [&](int j0){
        int c0 = (N_SEQ - 1) + j0 - i0 - 63;
        kr0 = *(const u16x8*)&Kg[(size_t)(j0 + sr)      * HD + h * DK + scv];
        kr1 = *(const u16x8*)&Kg[(size_t)(j0 + 32 + sr) * HD + h * DK + scv];
        vr0 = *(const u16x8*)&Vt[(size_t)(h * 64 + sr)      * N_SEQ + j0 + scv];
        vr1 = *(const u16x8*)&Vt[(size_t)(h * 64 + 32 + sr) * N_SEQ + j0 + scv];
        rr0 = *(const u16x8*)&RK[(size_t)(c0 + sr)      * HD + h * DK + scv];
        rr1 = *(const u16x8*)&RK[(size_t)(c0 + 32 + sr) * HD + h * DK + scv];
        rr2 = *(const u16x8*)&RK[(size_t)(c0 + 64 + sr) * HD + h * DK + scv];
        rr3 = *(const u16x8*)&RK[(size_t)(c0 + 96 + sr) * HD + h * DK + scv];
    };
    auto STORE = [&](){
        *(u16x8*)&Ks [(sr)      * 72 + scv] = kr0;
        *(u16x8*)&Ks [(32 + sr) * 72 + scv] = kr1;
        *(u16x8*)&Vts[(sr)      * 72 + scv] = vr0;
        *(u16x8*)&Vts[(32 + sr) * 72 + scv] = vr1;
        *(u16x8*)&Rs [(sr)      * 72 + scv] = rr0;
        *(u16x8*)&Rs [(32 + sr) * 72 + scv] = rr1;
        *(u16x8*)&Rs [(64 + sr) * 72 + scv] = rr2;
        *(u16x8*)&Rs [(96 + sr) * 72 + scv] = rr3;
    };

    float mrow[4] = {-1e9f, -1e9f, -1e9f, -1e9f};
    float lrow[4] = {0.f, 0.f, 0.f, 0.f};
    f32x4 oacc[4] = {{0,0,0,0},{0,0,0,0},{0,0,0,0},{0,0,0,0}};
    int iiBase = w * 16 + qd * 4;

    LOAD(jbase);
    STORE();
    for (int kt = 0; kt < NT; ++kt){
        __syncthreads();                       // tile kt staged & visible
        if (kt + 1 < NT) LOAD(jbase + (kt + 1) * 64);   // prefetch (latency hidden)

        // content logits S (16x64 strip per wave)
        f32x4 s[4] = {{0,0,0,0},{0,0,0,0},{0,0,0,0},{0,0,0,0}};
        #pragma unroll
        for (int nt = 0; nt < 4; ++nt)
            #pragma unroll
            for (int kc = 0; kc < 2; ++kc){
                bf16x8 b = ldfrag(&Ks[(nt * 16 + l15) * 72 + kc * 32 + qd * 8]);
                s[nt] = __builtin_amdgcn_mfma_f32_16x16x32_bf16(aqc[kc], b, s[nt], 0, 0, 0);
            }
        // rel strip T (16x128 per wave) -> LDS rows OWNED by this wave
        #pragma unroll
        for (int tt = 0; tt < 8; ++tt){
            f32x4 tv = {0, 0, 0, 0};
            #pragma unroll
            for (int kc = 0; kc < 2; ++kc){
                bf16x8 b = ldfrag(&Rs[(tt * 16 + l15) * 72 + kc * 32 + qd * 8]);
                tv = __builtin_amdgcn_mfma_f32_16x16x32_bf16(aqp[kc], b, tv, 0, 0, 0);
            }
            #pragma unroll
            for (int reg = 0; reg < 4; ++reg)
                Ts[(iiBase + reg) * 136 + tt * 16 + l15] = f2b(tv[reg]);
        }
        // no barrier: Ts rows written and read only by this wave (DS in-order)

        float sv[4][4];
        #pragma unroll
        for (int nt = 0; nt < 4; ++nt)
            #pragma unroll
            for (int reg = 0; reg < 4; ++reg){
                int ii = iiBase + reg;
                int jj = nt * 16 + l15;
                sv[nt][reg] = s[nt][reg] + b2f(Ts[ii * 136 + (jj - ii + 63)]);
            }

        // online softmax (reductions stay within the quad's 16 lanes)
        float mnew[4], alpha[4];
        #pragma unroll
        for (int reg = 0; reg < 4; ++reg){
            float mx = fmaxf(fmaxf(sv[0][reg], sv[1][reg]), fmaxf(sv[2][reg], sv[3][reg]));
            #pragma unroll
            for (int d = 1; d < 16; d <<= 1) mx = fmaxf(mx, __shfl_xor(mx, d));
            mnew[reg]  = fmaxf(mrow[reg], mx);
            alpha[reg] = __expf(mrow[reg] - mnew[reg]);
            mrow[reg]  = mnew[reg];
        }
        float psum[4] = {0.f, 0.f, 0.f, 0.f};
        #pragma unroll
        for (int nt = 0; nt < 4; ++nt)
            #pragma unroll
            for (int reg = 0; reg < 4; ++reg){
                float p = __expf(sv[nt][reg] - mnew[reg]);
                psum[reg] += p;
                Ps[(iiBase + reg) * 72 + nt * 16 + l15] = f2b(p);
            }
        #pragma unroll
        for (int reg = 0; reg < 4; ++reg){
            float ssum = psum[reg];
            #pragma unroll
            for (int d = 1; d < 16; d <<= 1) ssum += __shfl_xor(ssum, d);
            lrow[reg] = lrow[reg] * alpha[reg] + ssum;
        }
        #pragma unroll
        for (int nt = 0; nt < 4; ++nt)
            #pragma unroll
            for (int reg = 0; reg < 4; ++reg)
                oacc[nt][reg] *= alpha[reg];
        // no barrier: Ps rows written and read only by this wave

        // O += P @ V   (a-frag = own Ps rows; b-frag = Vts, staged at tile top)
        #pragma unroll
        for (int kc = 0; kc < 2; ++kc){
            bf16x8 a = ldfrag(&Ps[(w * 16 + l15) * 72 + kc * 32 + qd * 8]);
            #pragma unroll
            for (int nt = 0; nt < 4; ++nt){
                bf16x8 b = ldfrag(&Vts[(nt * 16 + l15) * 72 + kc * 32 + qd * 8]);
                oacc[nt] = __builtin_amdgcn_mfma_f32_16x16x32_bf16(a, b, oacc[nt], 0, 0, 0);
            }
        }
        __syncthreads();                       // all reads of tile kt done
        if (kt + 1 < NT) STORE();              // stage prefetched tile kt+1
    }

    // ---- write partials (unnormalized) ----
    size_t pb = ((size_t)half * 256 + bid) * 64;
    #pragma unroll
    for (int nt = 0; nt < 4; ++nt)
        #pragma unroll
        for (int reg = 0; reg < 4; ++reg)
            Opart[(pb + iiBase + reg) * 64 + nt * 16 + l15] = oacc[nt][reg];
    if (l15 == 0)
        #pragma unroll
        for (int reg = 0; reg < 4; ++reg){
            mpart[pb + iiBase + reg] = mrow[reg];
            lpart[pb + iiBase + reg] = lrow[reg];
        }
}

// ---------------------------------------------------------------------------
// Combine the two K-halves: O = (w1*O1 + w2*O2) / (w1*l1 + w2*l2), bf16 out.
// ---------------------------------------------------------------------------
__global__ __launch_bounds__(256) void combine_kernel(const float* __restrict__ Opart,
    const float* __restrict__ mpart, const float* __restrict__ lpart,
    u16* __restrict__ Oatt){
    int i0 = blockIdx.x * 64;
    int h  = blockIdx.y;
    int bid = blockIdx.x * NH + h;
    int t = threadIdx.x;
    int r = t >> 2, cb = (t & 3) * 16;
    size_t p1 = ((size_t)0   + bid) * 64 + r;
    size_t p2 = ((size_t)256 + bid) * 64 + r;
    float m1 = mpart[p1], m2 = mpart[p2];
    float l1 = lpart[p1], l2 = lpart[p2];
    float m  = fmaxf(m1, m2);
    float w1 = __expf(m1 - m), w2 = __expf(m2 - m);
    float inv = 1.0f / fmaxf(w1 * l1 + w2 * l2, 1e-30f);
    #pragma unroll
    for (int e = 0; e < 16; ++e){
        int c = cb + e;
        float o = (w1 * Opart[p1 * 64 + c] + w2 * Opart[p2 * 64 + c]) * inv;
        Oatt[(size_t)(i0 + r) * HD + h * DK + c] = f2b(o);
    }
}

// ---------------------------------------------------------------------------
// Output projection: out = Oattn @ Wo + bo. fp32 weights/bias/output.
// ---------------------------------------------------------------------------
__global__ __launch_bounds__(256) void oproj_kernel(const u16* __restrict__ A,
    const float* __restrict__ Wo, const float* __restrict__ bo,
    float* __restrict__ out, int m_base){
    __shared__ __align__(16) u16 xs[64 * 72];
    __shared__ __align__(16) u16 bs[64 * 72];
    int m0 = m_base + blockIdx.y * 64;
    int n0 = blockIdx.x * 64;
    int t = threadIdx.x;
    int w = t >> 6, lane = t & 63, qd = lane >> 4, l15 = lane & 15;
    f32x4 acc[4] = {{0,0,0,0},{0,0,0,0},{0,0,0,0},{0,0,0,0}};
    for (int k0 = 0; k0 < HD; k0 += 64){
        #pragma unroll
        for (int rep = 0; rep < 2; ++rep){
            int vid = rep * 256 + t;
            int r  = vid >> 3;
            int cv = (vid & 7) * 8;
            *(u16x8*)&xs[r * 72 + cv] = *(const u16x8*)&A[(size_t)(m0 + r) * HD + k0 + cv];
            size_t wi = (size_t)(k0 + r) * DIMM + n0 + cv;
            f32x4 wa = *(const f32x4*)(Wo + wi), wb = *(const f32x4*)(Wo + wi + 4);
            u16x8 wv;
            #pragma unroll
            for (int e = 0; e < 4; ++e){ wv[e] = f2b(wa[e]); wv[4 + e] = f2b(wb[e]); }
            #pragma unroll
            for (int e = 0; e < 8; ++e) bs[(cv + e) * 72 + r] = wv[e];
        }
        __syncthreads();
        bf16x8 a0 = ldfrag(&xs[(w * 16 + l15) * 72 +  0 + qd * 8]);
        bf16x8 a1 = ldfrag(&xs[(w * 16 + l15) * 72 + 32 + qd * 8]);
        #pragma unroll
        for (int nt = 0; nt < 4; ++nt){
            bf16x8 b0 = ldfrag(&bs[(nt * 16 + l15) * 72 +  0 + qd * 8]);
            bf16x8 b1 = ldfrag(&bs[(nt * 16 + l15) * 72 + 32 + qd * 8]);
            acc[nt] = __builtin_amdgcn_mfma_f32_16x16x32_bf16(a0, b0, acc[nt], 0, 0, 0);
            acc[nt] = __builtin_amdgcn_mfma_f32_16x16x32_bf16(a1, b1, acc[nt], 0, 0, 0);
        }
        __syncthreads();
    }
    #pragma unroll
    for (int nt = 0; nt < 4; ++nt)
        #pragma unroll
        for (int reg = 0; reg < 4; ++reg){
            int row = m0 + w * 16 + qd * 4 + reg;
            int col = n0 + nt * 16 + l15;
            out[(size_t)row * DIMM + col] = acc[nt][reg] + bo[col];
        }
}

extern "C" void kernel_launch(void* const* d_in, const int* in_sizes, int n_in,
                              void* d_out, int out_size, void* d_ws, size_t ws_size,
                              hipStream_t stream){
    const float* X  = (const float*)d_in[0];
    const float* Wq = (const float*)d_in[1];
    const float* Wk = (const float*)d_in[2];
    const float* Wv = (const float*)d_in[3];
    const float* Wr = (const float*)d_in[4];
    const float* Wo = (const float*)d_in[5];
    const float* bo = (const float*)d_in[6];
    const float* CB = (const float*)d_in[7];
    const float* PB = (const float*)d_in[8];
    float* out = (float*)d_out;

    // d_out = 6,291,456 fp32 = 12,582,912 u16.
    // bf16 scratch in the u16 TAIL (dead or consumed in row order):
    //   Q  u16 [ 6291456,  7340032)   Kb u16 [ 7340032,  8388608)
    //   Vt u16 [ 8388608,  9437184)   RK u16 [ 9437184, 11534336)
    //   Oatt u16 [11534336, 12582912)
    // fp32 HEAD holds attention partials (dead after combine):
    //   Opart fp32 [0, 2097152), mpart [2097152, 2129920), lpart [2129920, 2162688)
    u16* base = (u16*)d_out;
    u16* Q    = base + 6291456;
    u16* Kb   = base + 7340032;
    u16* Vt   = base + 8388608;
    u16* RK   = base + 9437184;
    u16* Oatt = base + 11534336;
    float* Opart = out;
    float* mpart = out + 2097152;
    float* lpart = out + 2129920;

    relk_kernel<<<dim3(2 * N_SEQ), 256, 0, stream>>>(Wr, RK);
    qkv_kernel<<<dim3(12, 64), 256, 0, stream>>>(X, Wq, Wk, Wv, Q, Kb, Vt);
    attn_kernel<<<dim3(64, NH, 2), 256, 0, stream>>>(Q, Kb, Vt, RK, CB, PB,
                                                     Opart, mpart, lpart);
    combine_kernel<<<dim3(64, NH), 256, 0, stream>>>(Opart, mpart, lpart, Oatt);

    // Copy last 64 Oatt rows (32 KB) to ws for the final oproj launch.
    u16* Acpy = (u16*)d_ws;
    hipMemcpyAsync(Acpy, Oatt + (size_t)4032 * HD, (size_t)64 * HD * sizeof(u16),
                   hipMemcpyDeviceToDevice, stream);

    // oproj split (u16 units): L1 rows [0,3712): writes end 11,403,264 <=
    // 11,534,336 (Oatt start). L2 rows [3712,4032): writes end 12,386,304 <=
    // 12,484,608 (Oatt row 3712) — clobbers only consumed Oatt rows and the
    // dead partial region. L3 rows [4032,4096): reads the ws copy.
    oproj_kernel<<<dim3(24, 58), 256, 0, stream>>>(Oatt, Wo, bo, out, 0);
    oproj_kernel<<<dim3(24,  5), 256, 0, stream>>>(Oatt, Wo, bo, out, 3712);
    oproj_kernel<<<dim3(24,  1), 256, 0, stream>>>(Acpy - (size_t)4032 * HD,
                                                   Wo, bo, out, 4032);
}

// Round 9
// 286.127 us; speedup vs baseline: 1.3642x; 1.0445x over previous
//
#include <hip/hip_runtime.h>
#include <hip/hip_bf16.h>

#define N_SEQ 4096
#define DIMM  1536
#define NH    4
#define DK    64
#define HD    256     // NH*DK
#define QK_SCALE 0.125f
#define WSZ   393216  // 1536*256 per weight

typedef __bf16 bf16x8 __attribute__((ext_vector_type(8)));
typedef unsigned short u16;
typedef u16   u16x8  __attribute__((ext_vector_type(8)));
typedef u16   u16x4  __attribute__((ext_vector_type(4)));
typedef float f32x4  __attribute__((ext_vector_type(4)));

__device__ inline float b2f(u16 u){
    union { float f; unsigned int i; } v; v.i = ((unsigned int)u) << 16; return v.f;
}
__device__ inline u16 f2b(float f){
    unsigned int x = __builtin_bit_cast(unsigned int, f);
    unsigned int r = (x + 0x7fffu + ((x >> 16) & 1u)) >> 16;
    return (u16)r;
}
__device__ inline bf16x8 ldfrag(const u16* p){
    return __builtin_bit_cast(bf16x8, *(const u16x8*)p);
}

// ---------------------------------------------------------------------------
// Convert Wq|Wk|Wv (fp32) -> Wb (bf16), 3*1536*256 elems, 8 per thread.
// ---------------------------------------------------------------------------
__global__ __launch_bounds__(256) void convw_kernel(const float* __restrict__ Wq,
    const float* __restrict__ Wk, const float* __restrict__ Wv, u16* __restrict__ Wb){
    int idx = (blockIdx.x * 256 + threadIdx.x) * 8;   // 576 blocks
    int s = idx / WSZ, off = idx % WSZ;
    const float* W = (s == 0) ? Wq : (s == 1 ? Wk : Wv);
    f32x4 a = *(const f32x4*)(W + off), b = *(const f32x4*)(W + off + 4);
    u16x8 o;
    #pragma unroll
    for (int e = 0; e < 4; ++e){ o[e] = f2b(a[e]); o[4 + e] = f2b(b[e]); }
    *(u16x8*)&Wb[idx] = o;
}

// ---------------------------------------------------------------------------
// fmtab[ad] = #{f in [0,32): cw[f] <= ad}, cw[f] = (n+1)^((f+1)/32) - 1.
// Same fp32 formula as the verified relk path.
// ---------------------------------------------------------------------------
__global__ __launch_bounds__(256) void fmtab_kernel(unsigned char* __restrict__ fmt){
    int d = blockIdx.x * 256 + threadIdx.x;           // 16 blocks -> 4096
    float lg = logf((float)(N_SEQ + 1)) * (1.0f / 32.0f);
    float ad = (float)d;
    int fm = 0;
    for (int f = 0; f < 32; ++f){
        float cw = expf(lg * (float)(f + 1)) - 1.0f;
        fm += (cw <= ad) ? 1 : 0;
    }
    fmt[d] = (unsigned char)fm;
}

// ---------------------------------------------------------------------------
// Fused QKV: one block per (n0, m0) computes all three projections.
// fp32 X staged->bf16; W read pre-converted bf16. V stored transposed.
// ---------------------------------------------------------------------------
__global__ __launch_bounds__(256) void qkv_kernel(const float* __restrict__ X,
    const u16* __restrict__ Wb,
    u16* __restrict__ Q, u16* __restrict__ K, u16* __restrict__ Vt){
    __shared__ __align__(16) u16 xs[64 * 72];
    __shared__ __align__(16) u16 bs[3 * 64 * 72];
    int n0 = blockIdx.x * 64;
    int m0 = blockIdx.y * 64;
    int t = threadIdx.x;
    int w = t >> 6, lane = t & 63, qd = lane >> 4, l15 = lane & 15;
    f32x4 acc[3][4];
    #pragma unroll
    for (int s = 0; s < 3; ++s)
        #pragma unroll
        for (int nt = 0; nt < 4; ++nt) acc[s][nt] = (f32x4){0,0,0,0};
    for (int k0 = 0; k0 < DIMM; k0 += 64){
        #pragma unroll
        for (int rep = 0; rep < 2; ++rep){
            int vid = rep * 256 + t;
            int r  = vid >> 3;
            int cv = (vid & 7) * 8;
            size_t xi = (size_t)(m0 + r) * DIMM + k0 + cv;
            f32x4 xa = *(const f32x4*)(X + xi), xb = *(const f32x4*)(X + xi + 4);
            u16x8 xv;
            #pragma unroll
            for (int e = 0; e < 4; ++e){ xv[e] = f2b(xa[e]); xv[4 + e] = f2b(xb[e]); }
            *(u16x8*)&xs[r * 72 + cv] = xv;
            #pragma unroll
            for (int s = 0; s < 3; ++s){
                u16x8 wv = *(const u16x8*)&Wb[(size_t)s * WSZ + (size_t)(k0 + r) * HD + n0 + cv];
                #pragma unroll
                for (int e = 0; e < 8; ++e) bs[s * 4608 + (cv + e) * 72 + r] = wv[e];
            }
        }
        __syncthreads();
        bf16x8 a0 = ldfrag(&xs[(w * 16 + l15) * 72 +  0 + qd * 8]);
        bf16x8 a1 = ldfrag(&xs[(w * 16 + l15) * 72 + 32 + qd * 8]);
        #pragma unroll
        for (int s = 0; s < 3; ++s)
            #pragma unroll
            for (int nt = 0; nt < 4; ++nt){
                bf16x8 b0 = ldfrag(&bs[s * 4608 + (nt * 16 + l15) * 72 +  0 + qd * 8]);
                bf16x8 b1 = ldfrag(&bs[s * 4608 + (nt * 16 + l15) * 72 + 32 + qd * 8]);
                acc[s][nt] = __builtin_amdgcn_mfma_f32_16x16x32_bf16(a0, b0, acc[s][nt], 0, 0, 0);
                acc[s][nt] = __builtin_amdgcn_mfma_f32_16x16x32_bf16(a1, b1, acc[s][nt], 0, 0, 0);
            }
        __syncthreads();
    }
    // epilogue
    int row0 = m0 + w * 16 + qd * 4;
    #pragma unroll
    for (int nt = 0; nt < 4; ++nt){
        int col = n0 + nt * 16 + l15;
        #pragma unroll
        for (int reg = 0; reg < 4; ++reg){
            Q[(size_t)(row0 + reg) * HD + col] = f2b(acc[0][nt][reg] * QK_SCALE);
            K[(size_t)(row0 + reg) * HD + col] = f2b(acc[1][nt][reg]);
        }
        u16x4 pv;
        #pragma unroll
        for (int reg = 0; reg < 4; ++reg) pv[reg] = f2b(acc[2][nt][reg]);
        *(u16x4*)&Vt[(size_t)col * N_SEQ + row0] = pv;
    }
}

// ---------------------------------------------------------------------------
// Flash attention, K-split 4-way, suffix-sum rel logits (no RK table).
// LDS 39.5 KB -> 4 blocks/CU. Block = (64 q-rows, head, quarter).
// ---------------------------------------------------------------------------
__global__ __launch_bounds__(256) void attn_kernel(const u16* __restrict__ Q,
    const u16* __restrict__ Kg, const u16* __restrict__ Vt,
    const float* __restrict__ Wrel, const unsigned char* __restrict__ fmtg,
    const float* __restrict__ CB, const float* __restrict__ PB,
    u16* __restrict__ OpU, float* __restrict__ mpart, float* __restrict__ lpart){
    __shared__ __align__(16) unsigned char smem[40448];
    u16* Ks   = (u16*)(smem + 0);         // 9216  (init: qcs / Uf)
    u16* Vts  = (u16*)(smem + 9216);      // 9216  (init: qps / Uf)
    u16* Ps   = (u16*)(smem + 18432);     // 9216  (init: Wrs)
    u16* relP = (u16*)(smem + 27648);     // 64*34*2 = 4352
    u16* relM = (u16*)(smem + 32000);     // 4352
    unsigned char* fmt = smem + 36352;    // 4096 -> end 40448
    u16* qcs = Ks;
    u16* qps = Vts;
    u16* Wrs = Ps;
    float* Uf = (float*)smem;             // 64*65*4 = 16640 (overlays Ks+Vts)

    int i0   = blockIdx.x * 64;
    int h    = blockIdx.y;
    int half = blockIdx.z;                // 0..3
    int bid  = blockIdx.x * NH + h;
    int jbase = half * (N_SEQ / 4);
    const int NT = (N_SEQ / 4) / 64;      // 16 tiles
    int t = threadIdx.x;
    int w = t >> 6, lane = t & 63, qd = lane >> 4, l15 = lane & 15;
    int iiBase = w * 16 + qd * 4;

    // ---- first tile global loads in flight during init ----
    int sr = t >> 3, scv = (t & 7) * 8;
    u16x8 kr0, kr1, vr0, vr1;
    auto LOAD = [&](int j0){
        kr0 = *(const u16x8*)&Kg[(size_t)(j0 + sr)      * HD + h * DK + scv];
        kr1 = *(const u16x8*)&Kg[(size_t)(j0 + 32 + sr) * HD + h * DK + scv];
        vr0 = *(const u16x8*)&Vt[(size_t)(h * 64 + sr)      * N_SEQ + j0 + scv];
        vr1 = *(const u16x8*)&Vt[(size_t)(h * 64 + 32 + sr) * N_SEQ + j0 + scv];
    };
    auto STORE = [&](){
        *(u16x8*)&Ks [(sr)      * 72 + scv] = kr0;
        *(u16x8*)&Ks [(32 + sr) * 72 + scv] = kr1;
        *(u16x8*)&Vts[(sr)      * 72 + scv] = vr0;
        *(u16x8*)&Vts[(32 + sr) * 72 + scv] = vr1;
    };
    LOAD(jbase);

    // ---- init: qc/qp staging, Wrel slice (bf16), fmtab to LDS ----
    #pragma unroll
    for (int rep = 0; rep < 2; ++rep){
        int vid = rep * 256 + t;
        int r  = vid >> 3;
        int cv = (vid & 7) * 8;
        u16x8 qv = *(const u16x8*)&Q[(size_t)(i0 + r) * HD + h * DK + cv];
        u16x8 oc, op;
        #pragma unroll
        for (int e = 0; e < 8; ++e){
            float qf = b2f(qv[e]);
            oc[e] = f2b(qf + CB[h * DK + cv + e]);
            op[e] = f2b(qf + PB[h * DK + cv + e]);
        }
        *(u16x8*)&qcs[r * 72 + cv] = oc;
        *(u16x8*)&qps[r * 72 + cv] = op;
        // Wrel slice: rows = feature f (64), cols = d (this head's 64)
        const float* wr = Wrel + (size_t)r * HD + h * DK + cv;
        f32x4 wa = *(const f32x4*)wr, wb = *(const f32x4*)(wr + 4);
        u16x8 wv;
        #pragma unroll
        for (int e = 0; e < 4; ++e){ wv[e] = f2b(wa[e]); wv[4 + e] = f2b(wb[e]); }
        *(u16x8*)&Wrs[r * 72 + cv] = wv;
    }
    ((uint4*)fmt)[t] = ((const uint4*)fmtg)[t];   // 4096 B
    __syncthreads();
    bf16x8 aqc[2], aqp[2];
    #pragma unroll
    for (int kc = 0; kc < 2; ++kc){
        aqc[kc] = ldfrag(&qcs[(w * 16 + l15) * 72 + kc * 32 + qd * 8]);
        aqp[kc] = ldfrag(&qps[(w * 16 + l15) * 72 + kc * 32 + qd * 8]);
    }
    __syncthreads();   // all frags in regs before Uf overwrites qcs/qps

    // ---- U = qp @ Wrel^T (C: row=q-row, col=feature) -> Uf fp32 ----
    #pragma unroll
    for (int nt = 0; nt < 4; ++nt){
        f32x4 u = {0, 0, 0, 0};
        #pragma unroll
        for (int kc = 0; kc < 2; ++kc){
            bf16x8 b = ldfrag(&Wrs[(nt * 16 + l15) * 72 + kc * 32 + qd * 8]);
            u = __builtin_amdgcn_mfma_f32_16x16x32_bf16(aqp[kc], b, u, 0, 0, 0);
        }
        #pragma unroll
        for (int reg = 0; reg < 4; ++reg)
            Uf[(iiBase + reg) * 65 + nt * 16 + l15] = u[reg];
    }
    __syncthreads();

    // ---- per-row suffix sums -> relP/relM bf16 tables ----
    if (t < 64){
        float s1 = 0.f, s2 = 0.f;
        relP[t * 34 + 32] = 0; relM[t * 34 + 32] = 0;
        for (int fm = 31; fm >= 0; --fm){
            s1 += Uf[t * 65 + fm];
            s2 += Uf[t * 65 + 32 + fm];
            relP[t * 34 + fm] = f2b(s1 + s2);
            relM[t * 34 + fm] = f2b(s1 - s2);
        }
        relP[t * 34 + 33] = f2b(s1);   // d == 0 case (sign = 0)
    }
    __syncthreads();

    // ---- main K-loop ----
    float mrow[4] = {-1e9f, -1e9f, -1e9f, -1e9f};
    float lrow[4] = {0.f, 0.f, 0.f, 0.f};
    f32x4 oacc[4] = {{0,0,0,0},{0,0,0,0},{0,0,0,0},{0,0,0,0}};

    STORE();
    for (int kt = 0; kt < NT; ++kt){
        __syncthreads();                              // tile kt visible
        int j0 = jbase + kt * 64;
        if (kt + 1 < NT) LOAD(j0 + 64);               // prefetch

        f32x4 s[4] = {{0,0,0,0},{0,0,0,0},{0,0,0,0},{0,0,0,0}};
        #pragma unroll
        for (int nt = 0; nt < 4; ++nt)
            #pragma unroll
            for (int kc = 0; kc < 2; ++kc){
                bf16x8 b = ldfrag(&Ks[(nt * 16 + l15) * 72 + kc * 32 + qd * 8]);
                s[nt] = __builtin_amdgcn_mfma_f32_16x16x32_bf16(aqc[kc], b, s[nt], 0, 0, 0);
            }

        // merge rel logits via table lookups
        float sv[4][4];
        #pragma unroll
        for (int nt = 0; nt < 4; ++nt){
            int jj = nt * 16 + l15;
            #pragma unroll
            for (int reg = 0; reg < 4; ++reg){
                int ii = iiBase + reg;
                int dd = (j0 + jj) - (i0 + ii);
                int ad = dd < 0 ? -dd : dd;
                int fm = fmt[ad];
                int idx = ii * 34 + ((dd == 0) ? 33 : fm);
                const u16* tab = (dd >= 0) ? relP : relM;
                sv[nt][reg] = s[nt][reg] + b2f(tab[idx]);
            }
        }

        // online softmax
        float mnew[4], alpha[4];
        #pragma unroll
        for (int reg = 0; reg < 4; ++reg){
            float mx = fmaxf(fmaxf(sv[0][reg], sv[1][reg]), fmaxf(sv[2][reg], sv[3][reg]));
            #pragma unroll
            for (int d = 1; d < 16; d <<= 1) mx = fmaxf(mx, __shfl_xor(mx, d));
            mnew[reg]  = fmaxf(mrow[reg], mx);
            alpha[reg] = __expf(mrow[reg] - mnew[reg]);
            mrow[reg]  = mnew[reg];
        }
        float psum[4] = {0.f, 0.f, 0.f, 0.f};
        #pragma unroll
        for (int nt = 0; nt < 4; ++nt)
            #pragma unroll
            for (int reg = 0; reg < 4; ++reg){
                float p = __expf(sv[nt][reg] - mnew[reg]);
                psum[reg] += p;
                Ps[(iiBase + reg) * 72 + nt * 16 + l15] = f2b(p);
            }
        #pragma unroll
        for (int reg = 0; reg < 4; ++reg){
            float ssum = psum[reg];
            #pragma unroll
            for (int d = 1; d < 16; d <<= 1) ssum += __shfl_xor(ssum, d);
            lrow[reg] = lrow[reg] * alpha[reg] + ssum;
        }
        #pragma unroll
        for (int nt = 0; nt < 4; ++nt)
            #pragma unroll
            for (int reg = 0; reg < 4; ++reg)
                oacc[nt][reg] *= alpha[reg];

        // O += P @ V (Ps rows intra-wave: DS in-order, no barrier needed)
        #pragma unroll
        for (int kc = 0; kc < 2; ++kc){
            bf16x8 a = ldfrag(&Ps[(w * 16 + l15) * 72 + kc * 32 + qd * 8]);
            #pragma unroll
            for (int nt = 0; nt < 4; ++nt){
                bf16x8 b = ldfrag(&Vts[(nt * 16 + l15) * 72 + kc * 32 + qd * 8]);
                oacc[nt] = __builtin_amdgcn_mfma_f32_16x16x32_bf16(a, b, oacc[nt], 0, 0, 0);
            }
        }
        __syncthreads();                              // reads of tile kt done
        if (kt + 1 < NT) STORE();
    }

    // ---- write partials: O (bf16, unnormalized), m, l ----
    size_t pb = ((size_t)half * 256 + bid) * 64;
    #pragma unroll
    for (int nt = 0; nt < 4; ++nt)
        #pragma unroll
        for (int reg = 0; reg < 4; ++reg)
            OpU[(pb + iiBase + reg) * 64 + nt * 16 + l15] = f2b(oacc[nt][reg]);
    if (l15 == 0)
        #pragma unroll
        for (int reg = 0; reg < 4; ++reg){
            mpart[pb + iiBase + reg] = mrow[reg];
            lpart[pb + iiBase + reg] = lrow[reg];
        }
}

// ---------------------------------------------------------------------------
// Combine 4 K-quarters -> normalized bf16 Oatt.
// ---------------------------------------------------------------------------
__global__ __launch_bounds__(256) void combine_kernel(const u16* __restrict__ OpU,
    const float* __restrict__ mpart, const float* __restrict__ lpart,
    u16* __restrict__ Oatt){
    int i0 = blockIdx.x * 64;
    int h  = blockIdx.y;
    int bid = blockIdx.x * NH + h;
    int t = threadIdx.x;
    int r = t >> 2, cb = (t & 3) * 16;
    size_t pr[4];
    float ms[4], ls[4];
    float m = -1e30f;
    #pragma unroll
    for (int s = 0; s < 4; ++s){
        pr[s] = ((size_t)s * 256 + bid) * 64 + r;
        ms[s] = mpart[pr[s]];
        ls[s] = lpart[pr[s]];
        m = fmaxf(m, ms[s]);
    }
    float den = 0.f, wgt[4];
    #pragma unroll
    for (int s = 0; s < 4; ++s){ wgt[s] = __expf(ms[s] - m); den += wgt[s] * ls[s]; }
    float inv = 1.0f / fmaxf(den, 1e-30f);
    float o[16];
    #pragma unroll
    for (int e = 0; e < 16; ++e) o[e] = 0.f;
    #pragma unroll
    for (int s = 0; s < 4; ++s){
        u16x8 a = *(const u16x8*)&OpU[pr[s] * 64 + cb];
        u16x8 b = *(const u16x8*)&OpU[pr[s] * 64 + cb + 8];
        #pragma unroll
        for (int e = 0; e < 8; ++e){
            o[e]     += wgt[s] * b2f(a[e]);
            o[8 + e] += wgt[s] * b2f(b[e]);
        }
    }
    u16x8 r0, r1;
    #pragma unroll
    for (int e = 0; e < 8; ++e){ r0[e] = f2b(o[e] * inv); r1[e] = f2b(o[8 + e] * inv); }
    size_t ob = (size_t)(i0 + r) * HD + h * DK + cb;
    *(u16x8*)&Oatt[ob]     = r0;
    *(u16x8*)&Oatt[ob + 8] = r1;
}

// ---------------------------------------------------------------------------
// Output projection: out = Oattn @ Wo + bo (fp32 W/bias/out).
// ---------------------------------------------------------------------------
__global__ __launch_bounds__(256) void oproj_kernel(const u16* __restrict__ A,
    const float* __restrict__ Wo, const float* __restrict__ bo,
    float* __restrict__ out, int m_base){
    __shared__ __align__(16) u16 xs[64 * 72];
    __shared__ __align__(16) u16 bs[64 * 72];
    int m0 = m_base + blockIdx.y * 64;
    int n0 = blockIdx.x * 64;
    int t = threadIdx.x;
    int w = t >> 6, lane = t & 63, qd = lane >> 4, l15 = lane & 15;
    f32x4 acc[4] = {{0,0,0,0},{0,0,0,0},{0,0,0,0},{0,0,0,0}};
    for (int k0 = 0; k0 < HD; k0 += 64){
        #pragma unroll
        for (int rep = 0; rep < 2; ++rep){
            int vid = rep * 256 + t;
            int r  = vid >> 3;
            int cv = (vid & 7) * 8;
            *(u16x8*)&xs[r * 72 + cv] = *(const u16x8*)&A[(size_t)(m0 + r) * HD + k0 + cv];
            size_t wi = (size_t)(k0 + r) * DIMM + n0 + cv;
            f32x4 wa = *(const f32x4*)(Wo + wi), wb = *(const f32x4*)(Wo + wi + 4);
            u16x8 wv;
            #pragma unroll
            for (int e = 0; e < 4; ++e){ wv[e] = f2b(wa[e]); wv[4 + e] = f2b(wb[e]); }
            #pragma unroll
            for (int e = 0; e < 8; ++e) bs[(cv + e) * 72 + r] = wv[e];
        }
        __syncthreads();
        bf16x8 a0 = ldfrag(&xs[(w * 16 + l15) * 72 +  0 + qd * 8]);
        bf16x8 a1 = ldfrag(&xs[(w * 16 + l15) * 72 + 32 + qd * 8]);
        #pragma unroll
        for (int nt = 0; nt < 4; ++nt){
            bf16x8 b0 = ldfrag(&bs[(nt * 16 + l15) * 72 +  0 + qd * 8]);
            bf16x8 b1 = ldfrag(&bs[(nt * 16 + l15) * 72 + 32 + qd * 8]);
            acc[nt] = __builtin_amdgcn_mfma_f32_16x16x32_bf16(a0, b0, acc[nt], 0, 0, 0);
            acc[nt] = __builtin_amdgcn_mfma_f32_16x16x32_bf16(a1, b1, acc[nt], 0, 0, 0);
        }
        __syncthreads();
    }
    #pragma unroll
    for (int nt = 0; nt < 4; ++nt)
        #pragma unroll
        for (int reg = 0; reg < 4; ++reg){
            int row = m0 + w * 16 + qd * 4 + reg;
            int col = n0 + nt * 16 + l15;
            out[(size_t)row * DIMM + col] = acc[nt][reg] + bo[col];
        }
}

extern "C" void kernel_launch(void* const* d_in, const int* in_sizes, int n_in,
                              void* d_out, int out_size, void* d_ws, size_t ws_size,
                              hipStream_t stream){
    const float* X  = (const float*)d_in[0];
    const float* Wq = (const float*)d_in[1];
    const float* Wk = (const float*)d_in[2];
    const float* Wv = (const float*)d_in[3];
    const float* Wr = (const float*)d_in[4];
    const float* Wo = (const float*)d_in[5];
    const float* bo = (const float*)d_in[6];
    const float* CB = (const float*)d_in[7];
    const float* PB = (const float*)d_in[8];
    float* out = (float*)d_out;
    u16* base = (u16*)d_out;   // 12,582,912 u16 slots

    // Scratch layout in d_out (u16 indices), all dead before oproj clobbers:
    //   Qb    [0,        1048576)
    //   Kb    [1048576,  2097152)
    //   Vt    [2097152,  3145728)
    //   Wb    [3145728,  4325376)    3*1536*256 bf16
    //   OpU   [4325376,  8519680)    4*256*64*64 bf16 partials
    //   mpart fp32 @ u16 [8519680, 8650752)
    //   lpart fp32 @ u16 [8650752, 8781824)
    //   Oatt  [11534336, 12582912)   read by oproj (protected by split)
    u16* Qb   = base;
    u16* Kb   = base + 1048576;
    u16* Vt   = base + 2097152;
    u16* Wb   = base + 3145728;
    u16* OpU  = base + 4325376;
    float* mpart = out + 4259840;
    float* lpart = out + 4325376;
    u16* Oatt = base + 11534336;

    // d_ws: fmtab u8[4096] @ 0; Acpy (32 KB) @ 4096.
    unsigned char* fmtg = (unsigned char*)d_ws;
    u16* Acpy = (u16*)((char*)d_ws + 4096);

    convw_kernel<<<dim3(576), 256, 0, stream>>>(Wq, Wk, Wv, Wb);
    fmtab_kernel<<<dim3(16), 256, 0, stream>>>(fmtg);
    qkv_kernel<<<dim3(4, 64), 256, 0, stream>>>(X, Wb, Qb, Kb, Vt);
    attn_kernel<<<dim3(64, NH, 4), 256, 0, stream>>>(Qb, Kb, Vt, Wr, fmtg, CB, PB,
                                                     OpU, mpart, lpart);
    combine_kernel<<<dim3(64, NH), 256, 0, stream>>>(OpU, mpart, lpart, Oatt);

    // Copy last 64 Oatt rows to ws for the final oproj launch.
    hipMemcpyAsync(Acpy, Oatt + (size_t)4032 * HD, (size_t)64 * HD * sizeof(u16),
                   hipMemcpyDeviceToDevice, stream);

    // oproj split (u16 units): L1 rows [0,3712): writes end 11,403,264 <=
    // 11,534,336 (Oatt start). L2 rows [3712,4032): writes end 12,386,304 ->
    // clobbers only Oatt rows < 3328 (already consumed). L3: reads ws copy.
    oproj_kernel<<<dim3(24, 58), 256, 0, stream>>>(Oatt, Wo, bo, out, 0);
    oproj_kernel<<<dim3(24,  5), 256, 0, stream>>>(Oatt, Wo, bo, out, 3712);
    oproj_kernel<<<dim3(24,  1), 256, 0, stream>>>(Acpy - (size_t)4032 * HD,
                                                   Wo, bo, out, 4032);
}

// Round 10
// 282.730 us; speedup vs baseline: 1.3806x; 1.0120x over previous
//
#include <hip/hip_runtime.h>
#include <hip/hip_bf16.h>

#define N_SEQ 4096
#define DIMM  1536
#define NH    4
#define DK    64
#define HD    256     // NH*DK
#define QK_SCALE 0.125f
#define WSZ   393216  // 1536*256 per weight

typedef __bf16 bf16x8 __attribute__((ext_vector_type(8)));
typedef unsigned short u16;
typedef u16   u16x8  __attribute__((ext_vector_type(8)));
typedef u16   u16x4  __attribute__((ext_vector_type(4)));
typedef float f32x4  __attribute__((ext_vector_type(4)));

__device__ inline float b2f(u16 u){
    union { float f; unsigned int i; } v; v.i = ((unsigned int)u) << 16; return v.f;
}
__device__ inline u16 f2b(float f){
    __bf16 h = (__bf16)f;               // native cvt, RNE
    return __builtin_bit_cast(u16, h);
}
__device__ inline bf16x8 ldfrag(const u16* p){
    return __builtin_bit_cast(bf16x8, *(const u16x8*)p);
}

// ---------------------------------------------------------------------------
// Convert Wq|Wk|Wv (fp32, [k][n]) -> Wt (bf16, TRANSPOSED [n][k]).
// Scattered fp32 reads (L2-resident, 4.7 MB), coalesced bf16 writes.
// ---------------------------------------------------------------------------
__global__ __launch_bounds__(256) void convwt_kernel(const float* __restrict__ Wq,
    const float* __restrict__ Wk, const float* __restrict__ Wv, u16* __restrict__ Wt){
    int idx = (blockIdx.x * 256 + threadIdx.x) * 8;   // 576 blocks
    int s = idx / WSZ, off = idx % WSZ;
    int n = off / DIMM, k = off % DIMM;
    const float* W = (s == 0) ? Wq : (s == 1 ? Wk : Wv);
    u16x8 o;
    #pragma unroll
    for (int e = 0; e < 8; ++e) o[e] = f2b(W[(size_t)(k + e) * HD + n]);
    *(u16x8*)&Wt[idx] = o;
}

// ---------------------------------------------------------------------------
// fmtab[ad] = #{f in [0,32): cw[f] <= ad}
// ---------------------------------------------------------------------------
__global__ __launch_bounds__(256) void fmtab_kernel(unsigned char* __restrict__ fmt){
    int d = blockIdx.x * 256 + threadIdx.x;           // 16 blocks
    float lg = logf((float)(N_SEQ + 1)) * (1.0f / 32.0f);
    float ad = (float)d;
    int fm = 0;
    for (int f = 0; f < 32; ++f){
        float cw = expf(lg * (float)(f + 1)) - 1.0f;
        fm += (cw <= ad) ? 1 : 0;
    }
    fmt[d] = (unsigned char)fm;
}

// ---------------------------------------------------------------------------
// Fused QKV: one block per (n0, m0), all three projections; Wt pre-transposed
// bf16 so weight staging is pure b128 LDS writes. V stored transposed.
// ---------------------------------------------------------------------------
__global__ __launch_bounds__(256) void qkv_kernel(const float* __restrict__ X,
    const u16* __restrict__ Wt,
    u16* __restrict__ Q, u16* __restrict__ K, u16* __restrict__ Vt){
    __shared__ __align__(16) u16 xs[64 * 72];
    __shared__ __align__(16) u16 bs[3 * 64 * 72];
    int n0 = blockIdx.x * 64;
    int m0 = blockIdx.y * 64;
    int t = threadIdx.x;
    int w = t >> 6, lane = t & 63, qd = lane >> 4, l15 = lane & 15;
    f32x4 acc[3][4];
    #pragma unroll
    for (int s = 0; s < 3; ++s)
        #pragma unroll
        for (int nt = 0; nt < 4; ++nt) acc[s][nt] = (f32x4){0,0,0,0};
    for (int k0 = 0; k0 < DIMM; k0 += 64){
        #pragma unroll
        for (int rep = 0; rep < 2; ++rep){
            int vid = rep * 256 + t;
            int r  = vid >> 3;
            int cv = (vid & 7) * 8;
            size_t xi = (size_t)(m0 + r) * DIMM + k0 + cv;
            f32x4 xa = *(const f32x4*)(X + xi), xb = *(const f32x4*)(X + xi + 4);
            u16x8 xv;
            #pragma unroll
            for (int e = 0; e < 4; ++e){ xv[e] = f2b(xa[e]); xv[4 + e] = f2b(xb[e]); }
            *(u16x8*)&xs[r * 72 + cv] = xv;
            #pragma unroll
            for (int s = 0; s < 3; ++s){
                u16x8 wv = *(const u16x8*)&Wt[(size_t)s * WSZ + (size_t)(n0 + r) * DIMM + k0 + cv];
                *(u16x8*)&bs[s * 4608 + r * 72 + cv] = wv;
            }
        }
        __syncthreads();
        bf16x8 a0 = ldfrag(&xs[(w * 16 + l15) * 72 +  0 + qd * 8]);
        bf16x8 a1 = ldfrag(&xs[(w * 16 + l15) * 72 + 32 + qd * 8]);
        #pragma unroll
        for (int s = 0; s < 3; ++s)
            #pragma unroll
            for (int nt = 0; nt < 4; ++nt){
                bf16x8 b0 = ldfrag(&bs[s * 4608 + (nt * 16 + l15) * 72 +  0 + qd * 8]);
                bf16x8 b1 = ldfrag(&bs[s * 4608 + (nt * 16 + l15) * 72 + 32 + qd * 8]);
                acc[s][nt] = __builtin_amdgcn_mfma_f32_16x16x32_bf16(a0, b0, acc[s][nt], 0, 0, 0);
                acc[s][nt] = __builtin_amdgcn_mfma_f32_16x16x32_bf16(a1, b1, acc[s][nt], 0, 0, 0);
            }
        __syncthreads();
    }
    int row0 = m0 + w * 16 + qd * 4;
    #pragma unroll
    for (int nt = 0; nt < 4; ++nt){
        int col = n0 + nt * 16 + l15;
        #pragma unroll
        for (int reg = 0; reg < 4; ++reg){
            Q[(size_t)(row0 + reg) * HD + col] = f2b(acc[0][nt][reg] * QK_SCALE);
            K[(size_t)(row0 + reg) * HD + col] = f2b(acc[1][nt][reg]);
        }
        u16x4 pv;
        #pragma unroll
        for (int reg = 0; reg < 4; ++reg) pv[reg] = f2b(acc[2][nt][reg]);
        *(u16x4*)&Vt[(size_t)col * N_SEQ + row0] = pv;
    }
}

// ---------------------------------------------------------------------------
// Flash attention, K-split 4-way, suffix-sum rel logits with tile-uniform
// fast path; l accumulated via ones-MFMA (no sum shuffles).
// ---------------------------------------------------------------------------
__global__ __launch_bounds__(256) void attn_kernel(const u16* __restrict__ Q,
    const u16* __restrict__ Kg, const u16* __restrict__ Vt,
    const float* __restrict__ Wrel, const unsigned char* __restrict__ fmtg,
    const float* __restrict__ CB, const float* __restrict__ PB,
    u16* __restrict__ OpU, float* __restrict__ mpart, float* __restrict__ lpart){
    __shared__ __align__(16) unsigned char smem[40448];
    u16* Ks   = (u16*)(smem + 0);         // 9216  (init: qcs / Uf)
    u16* Vts  = (u16*)(smem + 9216);      // 9216  (init: qps / Uf)
    u16* Ps   = (u16*)(smem + 18432);     // 9216  (init: Wrs)
    u16* relP = (u16*)(smem + 27648);     // 4352
    u16* relM = (u16*)(smem + 32000);     // 4352
    unsigned char* fmt = smem + 36352;    // 4096 -> end 40448
    u16* qcs = Ks;
    u16* qps = Vts;
    u16* Wrs = Ps;
    float* Uf = (float*)smem;             // 64*65*4 overlays Ks+Vts

    int i0   = blockIdx.x * 64;
    int h    = blockIdx.y;
    int half = blockIdx.z;                // 0..3
    int bid  = blockIdx.x * NH + h;
    int jbase = half * (N_SEQ / 4);
    const int NT = (N_SEQ / 4) / 64;      // 16 tiles
    int t = threadIdx.x;
    int w = t >> 6, lane = t & 63, qd = lane >> 4, l15 = lane & 15;
    int iiBase = w * 16 + qd * 4;

    int sr = t >> 3, scv = (t & 7) * 8;
    u16x8 kr0, kr1, vr0, vr1;
    auto LOAD = [&](int j0){
        kr0 = *(const u16x8*)&Kg[(size_t)(j0 + sr)      * HD + h * DK + scv];
        kr1 = *(const u16x8*)&Kg[(size_t)(j0 + 32 + sr) * HD + h * DK + scv];
        vr0 = *(const u16x8*)&Vt[(size_t)(h * 64 + sr)      * N_SEQ + j0 + scv];
        vr1 = *(const u16x8*)&Vt[(size_t)(h * 64 + 32 + sr) * N_SEQ + j0 + scv];
    };
    auto STORE = [&](){
        *(u16x8*)&Ks [(sr)      * 72 + scv] = kr0;
        *(u16x8*)&Ks [(32 + sr) * 72 + scv] = kr1;
        *(u16x8*)&Vts[(sr)      * 72 + scv] = vr0;
        *(u16x8*)&Vts[(32 + sr) * 72 + scv] = vr1;
    };
    LOAD(jbase);

    // ---- init: qc/qp staging, Wrel slice (bf16), fmtab to LDS ----
    #pragma unroll
    for (int rep = 0; rep < 2; ++rep){
        int vid = rep * 256 + t;
        int r  = vid >> 3;
        int cv = (vid & 7) * 8;
        u16x8 qv = *(const u16x8*)&Q[(size_t)(i0 + r) * HD + h * DK + cv];
        u16x8 oc, op;
        #pragma unroll
        for (int e = 0; e < 8; ++e){
            float qf = b2f(qv[e]);
            oc[e] = f2b(qf + CB[h * DK + cv + e]);
            op[e] = f2b(qf + PB[h * DK + cv + e]);
        }
        *(u16x8*)&qcs[r * 72 + cv] = oc;
        *(u16x8*)&qps[r * 72 + cv] = op;
        const float* wr = Wrel + (size_t)r * HD + h * DK + cv;
        f32x4 wa = *(const f32x4*)wr, wb = *(const f32x4*)(wr + 4);
        u16x8 wv;
        #pragma unroll
        for (int e = 0; e < 4; ++e){ wv[e] = f2b(wa[e]); wv[4 + e] = f2b(wb[e]); }
        *(u16x8*)&Wrs[r * 72 + cv] = wv;
    }
    ((uint4*)fmt)[t] = ((const uint4*)fmtg)[t];
    __syncthreads();
    bf16x8 aqc[2], aqp[2];
    #pragma unroll
    for (int kc = 0; kc < 2; ++kc){
        aqc[kc] = ldfrag(&qcs[(w * 16 + l15) * 72 + kc * 32 + qd * 8]);
        aqp[kc] = ldfrag(&qps[(w * 16 + l15) * 72 + kc * 32 + qd * 8]);
    }
    __syncthreads();   // frags in regs before Uf overwrites qcs/qps

    // ---- U = qp @ Wrel^T -> Uf ----
    #pragma unroll
    for (int nt = 0; nt < 4; ++nt){
        f32x4 u = {0, 0, 0, 0};
        #pragma unroll
        for (int kc = 0; kc < 2; ++kc){
            bf16x8 b = ldfrag(&Wrs[(nt * 16 + l15) * 72 + kc * 32 + qd * 8]);
            u = __builtin_amdgcn_mfma_f32_16x16x32_bf16(aqp[kc], b, u, 0, 0, 0);
        }
        #pragma unroll
        for (int reg = 0; reg < 4; ++reg)
            Uf[(iiBase + reg) * 65 + nt * 16 + l15] = u[reg];
    }
    __syncthreads();

    // ---- per-row suffix sums -> relP/relM ----
    if (t < 64){
        float s1 = 0.f, s2 = 0.f;
        relP[t * 34 + 32] = 0; relM[t * 34 + 32] = 0;
        for (int fm = 31; fm >= 0; --fm){
            s1 += Uf[t * 65 + fm];
            s2 += Uf[t * 65 + 32 + fm];
            relP[t * 34 + fm] = f2b(s1 + s2);
            relM[t * 34 + fm] = f2b(s1 - s2);
        }
        relP[t * 34 + 33] = f2b(s1);   // d == 0
    }
    __syncthreads();

    // ---- main K-loop ----
    float mrow[4] = {-1e9f, -1e9f, -1e9f, -1e9f};
    f32x4 lacc = {0.f, 0.f, 0.f, 0.f};
    f32x4 oacc[4] = {{0,0,0,0},{0,0,0,0},{0,0,0,0},{0,0,0,0}};
    bf16x8 onesf;
    #pragma unroll
    for (int e = 0; e < 8; ++e) onesf[e] = (__bf16)1.0f;

    STORE();
    for (int kt = 0; kt < NT; ++kt){
        __syncthreads();
        int j0 = jbase + kt * 64;
        if (kt + 1 < NT) LOAD(j0 + 64);

        f32x4 s[4] = {{0,0,0,0},{0,0,0,0},{0,0,0,0},{0,0,0,0}};
        #pragma unroll
        for (int nt = 0; nt < 4; ++nt)
            #pragma unroll
            for (int kc = 0; kc < 2; ++kc){
                bf16x8 b = ldfrag(&Ks[(nt * 16 + l15) * 72 + kc * 32 + qd * 8]);
                s[nt] = __builtin_amdgcn_mfma_f32_16x16x32_bf16(aqc[kc], b, s[nt], 0, 0, 0);
            }

        // rel merge: tile-uniform fast path (wave-uniform branch)
        int D = j0 - i0;
        float sv[4][4];
        bool fast = false; int fmU = 0; const u16* tabU = relP;
        if (D >= 64){
            int fmA = fmt[D - 63], fmB = fmt[D + 63];
            fast = (fmA == fmB); fmU = fmA; tabU = relP;
        } else if (D <= -64){
            int fmA = fmt[-D - 63], fmB = fmt[-D + 63];
            fast = (fmA == fmB); fmU = fmA; tabU = relM;
        }
        if (fast){
            float relv[4];
            #pragma unroll
            for (int reg = 0; reg < 4; ++reg)
                relv[reg] = b2f(tabU[(iiBase + reg) * 34 + fmU]);
            #pragma unroll
            for (int nt = 0; nt < 4; ++nt)
                #pragma unroll
                for (int reg = 0; reg < 4; ++reg)
                    sv[nt][reg] = s[nt][reg] + relv[reg];
        } else {
            #pragma unroll
            for (int nt = 0; nt < 4; ++nt){
                int jj = nt * 16 + l15;
                #pragma unroll
                for (int reg = 0; reg < 4; ++reg){
                    int ii = iiBase + reg;
                    int dd = D + jj - ii;
                    int ad = dd < 0 ? -dd : dd;
                    int fm = fmt[ad];
                    int idx = ii * 34 + ((dd == 0) ? 33 : fm);
                    const u16* tab = (dd >= 0) ? relP : relM;
                    sv[nt][reg] = s[nt][reg] + b2f(tab[idx]);
                }
            }
        }

        // online softmax (max only; sum via ones-MFMA below)
        float mnew[4], alpha[4];
        #pragma unroll
        for (int reg = 0; reg < 4; ++reg){
            float mx = fmaxf(fmaxf(sv[0][reg], sv[1][reg]), fmaxf(sv[2][reg], sv[3][reg]));
            #pragma unroll
            for (int d = 1; d < 16; d <<= 1) mx = fmaxf(mx, __shfl_xor(mx, d));
            mnew[reg]  = fmaxf(mrow[reg], mx);
            alpha[reg] = __expf(mrow[reg] - mnew[reg]);
            mrow[reg]  = mnew[reg];
        }
        #pragma unroll
        for (int nt = 0; nt < 4; ++nt)
            #pragma unroll
            for (int reg = 0; reg < 4; ++reg){
                float p = __expf(sv[nt][reg] - mnew[reg]);
                Ps[(iiBase + reg) * 72 + nt * 16 + l15] = f2b(p);
            }
        #pragma unroll
        for (int reg = 0; reg < 4; ++reg) lacc[reg] *= alpha[reg];
        #pragma unroll
        for (int nt = 0; nt < 4; ++nt)
            #pragma unroll
            for (int reg = 0; reg < 4; ++reg)
                oacc[nt][reg] *= alpha[reg];

        // O += P @ V ; l += P @ 1  (Ps intra-wave: DS in-order, no barrier)
        #pragma unroll
        for (int kc = 0; kc < 2; ++kc){
            bf16x8 a = ldfrag(&Ps[(w * 16 + l15) * 72 + kc * 32 + qd * 8]);
            lacc = __builtin_amdgcn_mfma_f32_16x16x32_bf16(a, onesf, lacc, 0, 0, 0);
            #pragma unroll
            for (int nt = 0; nt < 4; ++nt){
                bf16x8 b = ldfrag(&Vts[(nt * 16 + l15) * 72 + kc * 32 + qd * 8]);
                oacc[nt] = __builtin_amdgcn_mfma_f32_16x16x32_bf16(a, b, oacc[nt], 0, 0, 0);
            }
        }
        __syncthreads();
        if (kt + 1 < NT) STORE();
    }

    // ---- write partials ----
    size_t pb = ((size_t)half * 256 + bid) * 64;
    #pragma unroll
    for (int nt = 0; nt < 4; ++nt)
        #pragma unroll
        for (int reg = 0; reg < 4; ++reg)
            OpU[(pb + iiBase + reg) * 64 + nt * 16 + l15] = f2b(oacc[nt][reg]);
    if (l15 == 0)
        #pragma unroll
        for (int reg = 0; reg < 4; ++reg){
            mpart[pb + iiBase + reg] = mrow[reg];
            lpart[pb + iiBase + reg] = lacc[reg];
        }
}

// ---------------------------------------------------------------------------
// Combine 4 K-quarters -> normalized bf16 Oatt.
// ---------------------------------------------------------------------------
__global__ __launch_bounds__(256) void combine_kernel(const u16* __restrict__ OpU,
    const float* __restrict__ mpart, const float* __restrict__ lpart,
    u16* __restrict__ Oatt){
    int i0 = blockIdx.x * 64;
    int h  = blockIdx.y;
    int bid = blockIdx.x * NH + h;
    int t = threadIdx.x;
    int r = t >> 2, cb = (t & 3) * 16;
    size_t pr[4];
    float ms[4], ls[4];
    float m = -1e30f;
    #pragma unroll
    for (int s = 0; s < 4; ++s){
        pr[s] = ((size_t)s * 256 + bid) * 64 + r;
        ms[s] = mpart[pr[s]];
        ls[s] = lpart[pr[s]];
        m = fmaxf(m, ms[s]);
    }
    float den = 0.f, wgt[4];
    #pragma unroll
    for (int s = 0; s < 4; ++s){ wgt[s] = __expf(ms[s] - m); den += wgt[s] * ls[s]; }
    float inv = 1.0f / fmaxf(den, 1e-30f);
    float o[16];
    #pragma unroll
    for (int e = 0; e < 16; ++e) o[e] = 0.f;
    #pragma unroll
    for (int s = 0; s < 4; ++s){
        u16x8 a = *(const u16x8*)&OpU[pr[s] * 64 + cb];
        u16x8 b = *(const u16x8*)&OpU[pr[s] * 64 + cb + 8];
        #pragma unroll
        for (int e = 0; e < 8; ++e){
            o[e]     += wgt[s] * b2f(a[e]);
            o[8 + e] += wgt[s] * b2f(b[e]);
        }
    }
    u16x8 r0, r1;
    #pragma unroll
    for (int e = 0; e < 8; ++e){ r0[e] = f2b(o[e] * inv); r1[e] = f2b(o[8 + e] * inv); }
    size_t ob = (size_t)(i0 + r) * HD + h * DK + cb;
    *(u16x8*)&Oatt[ob]     = r0;
    *(u16x8*)&Oatt[ob + 8] = r1;
}

// ---------------------------------------------------------------------------
// Output projection: out = Oattn @ Wo + bo (fp32 W/bias/out).
// ---------------------------------------------------------------------------
__global__ __launch_bounds__(256) void oproj_kernel(const u16* __restrict__ A,
    const float* __restrict__ Wo, const float* __restrict__ bo,
    float* __restrict__ out, int m_base){
    __shared__ __align__(16) u16 xs[64 * 72];
    __shared__ __align__(16) u16 bs[64 * 72];
    int m0 = m_base + blockIdx.y * 64;
    int n0 = blockIdx.x * 64;
    int t = threadIdx.x;
    int w = t >> 6, lane = t & 63, qd = lane >> 4, l15 = lane & 15;
    f32x4 acc[4] = {{0,0,0,0},{0,0,0,0},{0,0,0,0},{0,0,0,0}};
    for (int k0 = 0; k0 < HD; k0 += 64){
        #pragma unroll
        for (int rep = 0; rep < 2; ++rep){
            int vid = rep * 256 + t;
            int r  = vid >> 3;
            int cv = (vid & 7) * 8;
            *(u16x8*)&xs[r * 72 + cv] = *(const u16x8*)&A[(size_t)(m0 + r) * HD + k0 + cv];
            size_t wi = (size_t)(k0 + r) * DIMM + n0 + cv;
            f32x4 wa = *(const f32x4*)(Wo + wi), wb = *(const f32x4*)(Wo + wi + 4);
            u16x8 wv;
            #pragma unroll
            for (int e = 0; e < 4; ++e){ wv[e] = f2b(wa[e]); wv[4 + e] = f2b(wb[e]); }
            #pragma unroll
            for (int e = 0; e < 8; ++e) bs[(cv + e) * 72 + r] = wv[e];
        }
        __syncthreads();
        bf16x8 a0 = ldfrag(&xs[(w * 16 + l15) * 72 +  0 + qd * 8]);
        bf16x8 a1 = ldfrag(&xs[(w * 16 + l15) * 72 + 32 + qd * 8]);
        #pragma unroll
        for (int nt = 0; nt < 4; ++nt){
            bf16x8 b0 = ldfrag(&bs[(nt * 16 + l15) * 72 +  0 + qd * 8]);
            bf16x8 b1 = ldfrag(&bs[(nt * 16 + l15) * 72 + 32 + qd * 8]);
            acc[nt] = __builtin_amdgcn_mfma_f32_16x16x32_bf16(a0, b0, acc[nt], 0, 0, 0);
            acc[nt] = __builtin_amdgcn_mfma_f32_16x16x32_bf16(a1, b1, acc[nt], 0, 0, 0);
        }
        __syncthreads();
    }
    #pragma unroll
    for (int nt = 0; nt < 4; ++nt)
        #pragma unroll
        for (int reg = 0; reg < 4; ++reg){
            int row = m0 + w * 16 + qd * 4 + reg;
            int col = n0 + nt * 16 + l15;
            out[(size_t)row * DIMM + col] = acc[nt][reg] + bo[col];
        }
}

extern "C" void kernel_launch(void* const* d_in, const int* in_sizes, int n_in,
                              void* d_out, int out_size, void* d_ws, size_t ws_size,
                              hipStream_t stream){
    const float* X  = (const float*)d_in[0];
    const float* Wq = (const float*)d_in[1];
    const float* Wk = (const float*)d_in[2];
    const float* Wv = (const float*)d_in[3];
    const float* Wr = (const float*)d_in[4];
    const float* Wo = (const float*)d_in[5];
    const float* bo = (const float*)d_in[6];
    const float* CB = (const float*)d_in[7];
    const float* PB = (const float*)d_in[8];
    float* out = (float*)d_out;
    u16* base = (u16*)d_out;   // 12,582,912 u16 slots

    // d_out scratch layout (u16), all dead before oproj clobbers:
    //   Qb  [0, 1048576)  Kb [1048576, 2097152)  Vt [2097152, 3145728)
    //   Wt  [3145728, 4325376)   OpU [4325376, 8519680)
    //   mpart fp32 @ u16 [8519680, 8650752), lpart [8650752, 8781824)
    //   Oatt [11534336, 12582912)
    u16* Qb   = base;
    u16* Kb   = base + 1048576;
    u16* Vt   = base + 2097152;
    u16* Wt   = base + 3145728;
    u16* OpU  = base + 4325376;
    float* mpart = out + 4259840;
    float* lpart = out + 4325376;
    u16* Oatt = base + 11534336;

    unsigned char* fmtg = (unsigned char*)d_ws;
    u16* Acpy = (u16*)((char*)d_ws + 4096);

    convwt_kernel<<<dim3(576), 256, 0, stream>>>(Wq, Wk, Wv, Wt);
    fmtab_kernel<<<dim3(16), 256, 0, stream>>>(fmtg);
    qkv_kernel<<<dim3(4, 64), 256, 0, stream>>>(X, Wt, Qb, Kb, Vt);
    attn_kernel<<<dim3(64, NH, 4), 256, 0, stream>>>(Qb, Kb, Vt, Wr, fmtg, CB, PB,
                                                     OpU, mpart, lpart);
    combine_kernel<<<dim3(64, NH), 256, 0, stream>>>(OpU, mpart, lpart, Oatt);

    hipMemcpyAsync(Acpy, Oatt + (size_t)4032 * HD, (size_t)64 * HD * sizeof(u16),
                   hipMemcpyDeviceToDevice, stream);

    // oproj split (u16 units): L1 rows [0,3712) writes end 11,403,264 <=
    // 11,534,336 (Oatt start). L2 rows [3712,4032) clobbers only consumed
    // Oatt rows. L3 rows [4032,4096) reads the ws copy.
    oproj_kernel<<<dim3(24, 58), 256, 0, stream>>>(Oatt, Wo, bo, out, 0);
    oproj_kernel<<<dim3(24,  5), 256, 0, stream>>>(Oatt, Wo, bo, out, 3712);
    oproj_kernel<<<dim3(24,  1), 256, 0, stream>>>(Acpy - (size_t)4032 * HD,
                                                   Wo, bo, out, 4032);
}